// Round 3
// baseline (397.591 us; speedup 1.0000x reference)
//
#include <hip/hip_runtime.h>
#include <math.h>

#define K_DIM 1024
#define E_DIM 256

__device__ __forceinline__ void fma4(float4& a, const float4& b, float s) {
    a.x += b.x * s; a.y += b.y * s; a.z += b.z * s; a.w += b.w * s;
}

// ---------------------------------------------------------------------------
// Router: logits tile [64 tokens x 256 experts] fp32, emit per-token top-3
// candidate expert indices (approx order; exact ordering decided in refine).
// grid = N/64 blocks, 512 threads.
// ---------------------------------------------------------------------------
__global__ __launch_bounds__(512)
void router_kernel(const float* __restrict__ x, const float* __restrict__ w,
                   int* __restrict__ cand)
{
    __shared__ float4 Xs4[32][17];   // [kk][token/4], 68-float rows
    __shared__ float4 Ws4[32][65];   // [kk][e/4],     260-float rows
    float* Xsf = (float*)Xs4;
    float* Wsf = (float*)Ws4;

    const int tid = threadIdx.x;
    const int n0  = blockIdx.x * 64;
    const int tx  = tid & 31;        // expert group 0..31
    const int ty  = tid >> 5;        // token group 0..15

    float4 acc[4][2];
    #pragma unroll
    for (int i = 0; i < 4; ++i) {
        acc[i][0] = make_float4(0.f, 0.f, 0.f, 0.f);
        acc[i][1] = make_float4(0.f, 0.f, 0.f, 0.f);
    }

    for (int k0 = 0; k0 < K_DIM; k0 += 32) {
        // stage X chunk: 64 tokens x 32 k  (transposed to [kk][token])
        {
            const int t   = tid >> 3;
            const int kk4 = (tid & 7) * 4;
            float4 v = *(const float4*)(x + (size_t)(n0 + t) * K_DIM + k0 + kk4);
            Xsf[(kk4 + 0) * 68 + t] = v.x;
            Xsf[(kk4 + 1) * 68 + t] = v.y;
            Xsf[(kk4 + 2) * 68 + t] = v.z;
            Xsf[(kk4 + 3) * 68 + t] = v.w;
        }
        // stage W chunk: 256 experts x 32 k (transposed to [kk][e])
        {
            const int kk4 = (tid & 7) * 4;
            const int er  = tid >> 3;    // 0..63
            #pragma unroll
            for (int p = 0; p < 4; ++p) {
                const int e = p * 64 + er;
                float4 v = *(const float4*)(w + (size_t)e * K_DIM + k0 + kk4);
                Wsf[(kk4 + 0) * 260 + e] = v.x;
                Wsf[(kk4 + 1) * 260 + e] = v.y;
                Wsf[(kk4 + 2) * 260 + e] = v.z;
                Wsf[(kk4 + 3) * 260 + e] = v.w;
            }
        }
        __syncthreads();
        #pragma unroll 8
        for (int kk = 0; kk < 32; ++kk) {
            const float4 xv = Xs4[kk][ty];
            const float4 w0 = Ws4[kk][tx];
            const float4 w1 = Ws4[kk][tx + 32];
            const float xs[4] = {xv.x, xv.y, xv.z, xv.w};
            #pragma unroll
            for (int i = 0; i < 4; ++i) {
                fma4(acc[i][0], w0, xs[i]);
                fma4(acc[i][1], w1, xs[i]);
            }
        }
        __syncthreads();
    }

    // Per-token top-3 candidates. Token (ty*4+i) logits live in the 32 lanes
    // sharing ty (a half-wave); experts per lane: e = tx*4 + q + 128*j.
    #pragma unroll
    for (int i = 0; i < 4; ++i) {
        float v1 = -INFINITY, v2 = -INFINITY, v3 = -INFINITY;
        int   e1 = 0x7fffffff, e2 = 0x7fffffff, e3 = 0x7fffffff;
        #pragma unroll
        for (int j = 0; j < 2; ++j) {
            const float vs[4] = {acc[i][j].x, acc[i][j].y, acc[i][j].z, acc[i][j].w};
            #pragma unroll
            for (int q = 0; q < 4; ++q) {
                const float v = vs[q];
                const int   e = tx * 4 + q + j * 128;
                if (v > v1 || (v == v1 && e < e1)) {
                    v3 = v2; e3 = e2; v2 = v1; e2 = e1; v1 = v; e1 = e;
                } else if (v > v2 || (v == v2 && e < e2)) {
                    v3 = v2; e3 = e2; v2 = v; e2 = e;
                } else if (v > v3 || (v == v3 && e < e3)) {
                    v3 = v; e3 = e;
                }
            }
        }
        // butterfly merge across the 32 lanes of this token's half-wave
        #pragma unroll
        for (int m = 1; m <= 16; m <<= 1) {
            const float u1 = __shfl_xor(v1, m, 64);
            const float u2 = __shfl_xor(v2, m, 64);
            const float u3 = __shfl_xor(v3, m, 64);
            const int   f1 = __shfl_xor(e1, m, 64);
            const int   f2 = __shfl_xor(e2, m, 64);
            const int   f3 = __shfl_xor(e3, m, 64);
            float av[3] = {v1, v2, v3}, bv[3] = {u1, u2, u3};
            int   ae[3] = {e1, e2, e3}, be[3] = {f1, f2, f3};
            int pa = 0, pb = 0;
            float rv[3]; int re[3];
            #pragma unroll
            for (int s = 0; s < 3; ++s) {
                const float va_ = av[pa], vb_ = bv[pb];
                const int   ea_ = ae[pa], eb_ = be[pb];
                const bool ta = (va_ > vb_) || (va_ == vb_ && ea_ < eb_);
                rv[s] = ta ? va_ : vb_;
                re[s] = ta ? ea_ : eb_;
                pa += ta ? 1 : 0;
                pb += ta ? 0 : 1;
            }
            v1 = rv[0]; v2 = rv[1]; v3 = rv[2];
            e1 = re[0]; e2 = re[1]; e3 = re[2];
        }
        if (tx == 0) {
            const int n = n0 + ty * 4 + i;
            cand[n * 4 + 0] = e1;
            cand[n * 4 + 1] = e2;
            cand[n * 4 + 2] = e3;
        }
    }
}

// ---------------------------------------------------------------------------
// Refine: fp64 dots for the 3 candidates -> exact top-2 + softmax probs.
// grid = N blocks, 256 threads (4 waves; wave c handles candidate c, c=3 dup).
// ---------------------------------------------------------------------------
__global__ __launch_bounds__(256)
void refine_kernel(const float* __restrict__ x, const float* __restrict__ w,
                   const int* __restrict__ cand, int* __restrict__ ridx,
                   float* __restrict__ rprob)
{
    const int n   = blockIdx.x;
    const int tid = threadIdx.x;
    __shared__ int    sc[4];
    __shared__ double sv[4];
    if (tid < 3) sc[tid] = cand[n * 4 + tid];
    __syncthreads();
    const int c    = tid >> 6;
    const int lane = tid & 63;
    const int cc   = sc[(c < 3) ? c : 2];
    const float* xr = x + (size_t)n * K_DIM;
    const float* wr = w + (size_t)cc * K_DIM;
    double acc = 0.0;
    #pragma unroll
    for (int k = lane; k < K_DIM; k += 64)
        acc += (double)xr[k] * (double)wr[k];
    #pragma unroll
    for (int m = 32; m >= 1; m >>= 1) acc += __shfl_xor(acc, m, 64);
    if (lane == 0) sv[c] = acc;
    __syncthreads();
    if (tid == 0) {
        double v0 = sv[0], v1 = sv[1], v2 = sv[2];
        int    e0 = sc[0], e1 = sc[1], e2 = sc[2];
        const bool b01 = (v0 > v1) || (v0 == v1 && e0 < e1);
        double a0 = b01 ? v0 : v1, a1 = b01 ? v1 : v0;
        int    c0 = b01 ? e0 : e1, c1 = b01 ? e1 : e0;
        const bool b20 = (v2 > a0) || (v2 == a0 && e2 < c0);
        const bool b21 = (v2 > a1) || (v2 == a1 && e2 < c1);
        if (b20)      { a1 = a0; c1 = c0; a0 = v2; c0 = e2; }
        else if (b21) { a1 = v2; c1 = e2; }
        const double ex = exp(a1 - a0);
        const double p0 = 1.0 / (1.0 + ex);
        ridx[n * 2 + 0] = c0;
        ridx[n * 2 + 1] = c1;
        rprob[n * 2 + 0] = (float)p0;
        rprob[n * 2 + 1] = (float)(ex / (1.0 + ex));
    }
}

// ---------------------------------------------------------------------------
// Expert: per token, out = (p0*A0 X B0^T + p1*A1 X B1^T) * scale + bias.
// grid = N blocks, 256 threads. Thread owns Y[r][c4..c4+3].
// ---------------------------------------------------------------------------
__global__ __launch_bounds__(256)
void expert_kernel(const float* __restrict__ x, const float* __restrict__ Aexp,
                   const float* __restrict__ Bexp, const int* __restrict__ ridx,
                   const float* __restrict__ rprob, const float* __restrict__ scale,
                   const float* __restrict__ bias, float* __restrict__ out)
{
    __shared__ float4 Xs4[32][9];   // X [i1][i2], 36-float rows
    __shared__ float4 As4[32][9];   // A [o1][i1]
    __shared__ float4 BT4[32][9];   // B^T [i2][o2]
    __shared__ float4 Ts4[32][9];   // T = A@X [o1][i2]
    float* BTf = (float*)BT4;

    const int n   = blockIdx.x;
    const int tid = threadIdx.x;
    const int r   = tid >> 3;          // 0..31
    const int c4  = (tid & 7) * 4;     // 0,4,...,28

    {
        float4 v = *(const float4*)(x + (size_t)n * K_DIM + r * 32 + c4);
        Xs4[r][c4 >> 2] = v;
    }
    const int   ea = ridx[n * 2 + 0], eb = ridx[n * 2 + 1];
    const float pa = rprob[n * 2 + 0], pb = rprob[n * 2 + 1];

    float4 oacc = make_float4(0.f, 0.f, 0.f, 0.f);
    #pragma unroll
    for (int t = 0; t < 2; ++t) {
        const int   e = t ? eb : ea;
        const float p = t ? pb : pa;
        {
            float4 va = *(const float4*)(Aexp + (size_t)e * 1024 + r * 32 + c4);
            As4[r][c4 >> 2] = va;
            float4 vb = *(const float4*)(Bexp + (size_t)e * 1024 + r * 32 + c4);
            BTf[(c4 + 0) * 36 + r] = vb.x;
            BTf[(c4 + 1) * 36 + r] = vb.y;
            BTf[(c4 + 2) * 36 + r] = vb.z;
            BTf[(c4 + 3) * 36 + r] = vb.w;
        }
        __syncthreads();
        // T = A @ X
        float4 tacc = make_float4(0.f, 0.f, 0.f, 0.f);
        #pragma unroll
        for (int i0 = 0; i0 < 32; i0 += 4) {
            const float4 a4 = As4[r][i0 >> 2];
            const float4 x0 = Xs4[i0 + 0][c4 >> 2];
            const float4 x1 = Xs4[i0 + 1][c4 >> 2];
            const float4 x2 = Xs4[i0 + 2][c4 >> 2];
            const float4 x3 = Xs4[i0 + 3][c4 >> 2];
            fma4(tacc, x0, a4.x); fma4(tacc, x1, a4.y);
            fma4(tacc, x2, a4.z); fma4(tacc, x3, a4.w);
        }
        Ts4[r][c4 >> 2] = tacc;
        __syncthreads();
        // Y = T @ B^T  via BT[j][o2]
        float4 yacc = make_float4(0.f, 0.f, 0.f, 0.f);
        #pragma unroll
        for (int j0 = 0; j0 < 32; j0 += 4) {
            const float4 t4 = Ts4[r][j0 >> 2];
            const float4 b0 = BT4[j0 + 0][c4 >> 2];
            const float4 b1 = BT4[j0 + 1][c4 >> 2];
            const float4 b2 = BT4[j0 + 2][c4 >> 2];
            const float4 b3 = BT4[j0 + 3][c4 >> 2];
            fma4(yacc, b0, t4.x); fma4(yacc, b1, t4.y);
            fma4(yacc, b2, t4.z); fma4(yacc, b3, t4.w);
        }
        fma4(oacc, yacc, p);
        __syncthreads();
    }
    const float s  = scale[0];
    const float4 bb = *(const float4*)(bias + r * 32 + c4);
    float4 o;
    o.x = oacc.x * s + bb.x;
    o.y = oacc.y * s + bb.y;
    o.z = oacc.z * s + bb.z;
    o.w = oacc.w * s + bb.w;
    *(float4*)(out + (size_t)n * K_DIM + r * 32 + c4) = o;
}

extern "C" void kernel_launch(void* const* d_in, const int* in_sizes, int n_in,
                              void* d_out, int out_size, void* d_ws, size_t ws_size,
                              hipStream_t stream)
{
    const float* x     = (const float*)d_in[0];
    const float* rw    = (const float*)d_in[1];
    const float* Ae    = (const float*)d_in[2];
    const float* Be    = (const float*)d_in[3];
    const float* scale = (const float*)d_in[4];
    const float* bias  = (const float*)d_in[5];
    float* out = (float*)d_out;

    const int N = in_sizes[0] / K_DIM;   // 16384 tokens

    int*   cand  = (int*)d_ws;                    // N*4 ints
    int*   ridx  = cand + (size_t)N * 4;          // N*2 ints
    float* rprob = (float*)(ridx + (size_t)N * 2);// N*2 floats

    router_kernel<<<N / 64, 512, 0, stream>>>(x, rw, cand);
    refine_kernel<<<N, 256, 0, stream>>>(x, rw, cand, ridx, rprob);
    expert_kernel<<<N, 256, 0, stream>>>(x, Ae, Be, ridx, rprob, scale, bias, out);
}

// Round 4
// 323.052 us; speedup vs baseline: 1.2307x; 1.2307x over previous
//
#include <hip/hip_runtime.h>
#include <math.h>

#define KD 1024
#define ED 256

typedef __attribute__((ext_vector_type(8)))  short s16x8;
typedef __attribute__((ext_vector_type(4)))  float f32x4;
typedef __attribute__((ext_vector_type(16))) float f32x16;

__device__ __forceinline__ short f2bf(float f) {
    union { float f; unsigned u; } v; v.f = f;
    unsigned r = v.u + 0x7fffu + ((v.u >> 16) & 1u);
    return (short)(r >> 16);
}
__device__ __forceinline__ float bf2f(short s) {
    union { unsigned u; float f; } v; v.u = ((unsigned)(unsigned short)s) << 16;
    return v.f;
}

// ---------------------------------------------------------------------------
// Convert router_w fp32 -> bf16 once (256K elems).
// ---------------------------------------------------------------------------
__global__ __launch_bounds__(256)
void wconv_kernel(const float* __restrict__ w, short* __restrict__ wb, int n4) {
    int i = blockIdx.x * 256 + threadIdx.x;
    if (i < n4) {
        float4 v = ((const float4*)w)[i];
        short4 o;
        o.x = f2bf(v.x); o.y = f2bf(v.y); o.z = f2bf(v.z); o.w = f2bf(v.w);
        ((short4*)wb)[i] = o;
    }
}

// ---------------------------------------------------------------------------
// Router: 32 tokens x 256 experts per block via 16x16x32 bf16 MFMA.
// K chunked by 64, XOR-swizzled LDS (stride-128B rows -> G4 conflict fix).
// Epilogue: per-token top-8 candidates (approx); exact top-2 done in refine8.
// grid = N/32, block 256 (4 waves; wave w owns experts [w*64, w*64+64)).
// ---------------------------------------------------------------------------
__global__ __launch_bounds__(256)
void router_mfma(const float* __restrict__ x, const short* __restrict__ wb,
                 int* __restrict__ cand)
{
    __shared__ __align__(16) char smem[36864];
    char* XsB = smem;            // 32 rows x 128B  (bf16 [tok][k], swizzled)
    char* WsB = smem + 4096;     // 256 rows x 128B (bf16 [e][k],  swizzled)
    float* Ls = (float*)smem;    // 32 x 260 fp32 logits (reuses LDS after K-loop)

    const int tid  = threadIdx.x;
    const int lane = tid & 63;
    const int wv   = tid >> 6;
    const int n0   = blockIdx.x * 32;

    f32x4 acc[2][4];
    #pragma unroll
    for (int i = 0; i < 2; ++i)
        #pragma unroll
        for (int j = 0; j < 4; ++j)
            #pragma unroll
            for (int r = 0; r < 4; ++r) acc[i][j][r] = 0.f;

    const int stok = tid >> 3;        // 0..31 staging row
    const int skq  = (tid & 7) * 8;   // k offset 0..56
    const int xswz = (stok & 7) << 4;

    for (int ch = 0; ch < 16; ++ch) {
        // stage X chunk: 32 tok x 64 k, fp32->bf16
        {
            const float* xp = x + (size_t)(n0 + stok) * KD + ch * 64 + skq;
            float4 a = *(const float4*)xp;
            float4 b = *(const float4*)(xp + 4);
            s16x8 pk;
            pk[0] = f2bf(a.x); pk[1] = f2bf(a.y); pk[2] = f2bf(a.z); pk[3] = f2bf(a.w);
            pk[4] = f2bf(b.x); pk[5] = f2bf(b.y); pk[6] = f2bf(b.z); pk[7] = f2bf(b.w);
            *(s16x8*)(XsB + stok * 128 + ((skq * 2) ^ xswz)) = pk;
        }
        // stage W chunk: 256 e x 64 k (pre-converted bf16)
        #pragma unroll
        for (int p = 0; p < 8; ++p) {
            const int e = p * 32 + stok % 32;  // stok==tid>>3 spans 0..31
            s16x8 v = *(const s16x8*)(wb + (size_t)e * KD + ch * 64 + skq);
            *(s16x8*)(WsB + e * 128 + ((skq * 2) ^ ((e & 7) << 4))) = v;
        }
        __syncthreads();
        #pragma unroll
        for (int ks = 0; ks < 2; ++ks) {
            const int kbyte = ks * 64 + (lane >> 4) * 16;
            s16x8 af[2];
            #pragma unroll
            for (int fm = 0; fm < 2; ++fm) {
                const int tok = fm * 16 + (lane & 15);
                af[fm] = *(const s16x8*)(XsB + tok * 128 + (kbyte ^ ((tok & 7) << 4)));
            }
            #pragma unroll
            for (int fn = 0; fn < 4; ++fn) {
                const int e = wv * 64 + fn * 16 + (lane & 15);
                s16x8 bf = *(const s16x8*)(WsB + e * 128 + (kbyte ^ ((e & 7) << 4)));
                #pragma unroll
                for (int fm = 0; fm < 2; ++fm)
                    acc[fm][fn] = __builtin_amdgcn_mfma_f32_16x16x32_bf16(
                        af[fm], bf, acc[fm][fn], 0, 0, 0);
            }
        }
        __syncthreads();
    }

    // dump logits to LDS (C layout: col=lane&15, row=(lane>>4)*4+reg)
    #pragma unroll
    for (int fm = 0; fm < 2; ++fm)
        #pragma unroll
        for (int fn = 0; fn < 4; ++fn)
            #pragma unroll
            for (int r = 0; r < 4; ++r) {
                const int tok = fm * 16 + (lane >> 4) * 4 + r;
                const int e   = wv * 64 + fn * 16 + (lane & 15);
                Ls[tok * 260 + e] = acc[fm][fn][r];
            }
    __syncthreads();

    // top-8 per token: 8 threads/token, each scans 32 experts.
    const int t = tid >> 3;   // token 0..31
    const int s = tid & 7;    // segment
    float vv[8]; int ee[8];
    #pragma unroll
    for (int i = 0; i < 8; ++i) { vv[i] = -INFINITY; ee[i] = 0x7fffffff; }
    for (int q = 0; q < 32; ++q) {
        float tv = Ls[t * 260 + s * 32 + q];
        int   te = s * 32 + q;
        if ((tv > vv[7]) || (tv == vv[7] && te < ee[7])) {
            #pragma unroll
            for (int i = 0; i < 8; ++i) {
                bool g = (tv > vv[i]) || (tv == vv[i] && te < ee[i]);
                float fv = g ? vv[i] : tv; int fe = g ? ee[i] : te;
                vv[i] = g ? tv : vv[i];    ee[i] = g ? te : ee[i];
                tv = fv; te = fe;
            }
        }
    }
    int cnt = 0;
    #pragma unroll
    for (int it = 0; it < 8; ++it) {
        float cv = vv[0]; int ce = ee[0];
        #pragma unroll
        for (int i = 1; i < 8; ++i) {
            bool b = (cnt == i); cv = b ? vv[i] : cv; ce = b ? ee[i] : ce;
        }
        float bv = cv; int be = ce;
        #pragma unroll
        for (int m = 1; m <= 4; m <<= 1) {
            float ov = __shfl_xor(bv, m, 64);
            int   oe = __shfl_xor(be, m, 64);
            bool g = (ov > bv) || (ov == bv && oe < be);
            bv = g ? ov : bv; be = g ? oe : be;
        }
        if ((be >> 5) == s) cnt++;
        if (s == 0) cand[(size_t)(n0 + t) * 8 + it] = be;
    }
}

// ---------------------------------------------------------------------------
// Refine: fp64 dots for 8 candidates -> exact top-2 + softmax (verified anchor).
// grid = N, block 512 (wave c handles candidate c).
// ---------------------------------------------------------------------------
__global__ __launch_bounds__(512)
void refine8_kernel(const float* __restrict__ x, const float* __restrict__ w,
                    const int* __restrict__ cand, int* __restrict__ ridx,
                    float* __restrict__ rprob)
{
    const int n = blockIdx.x, tid = threadIdx.x;
    __shared__ int sc[8]; __shared__ double sv[8];
    if (tid < 8) sc[tid] = cand[(size_t)n * 8 + tid];
    __syncthreads();
    const int c = tid >> 6, lane = tid & 63;
    const int e = sc[c];
    const float* xr = x + (size_t)n * KD;
    const float* wr = w + (size_t)e * KD;
    double a = 0.0;
    #pragma unroll
    for (int k = lane; k < KD; k += 64) a += (double)xr[k] * (double)wr[k];
    #pragma unroll
    for (int m = 32; m >= 1; m >>= 1) a += __shfl_xor(a, m, 64);
    if (lane == 0) sv[c] = a;
    __syncthreads();
    if (tid == 0) {
        double b0 = -1e300, b1 = -1e300; int i0 = 0x7fffffff, i1 = 0x7fffffff;
        #pragma unroll
        for (int i = 0; i < 8; ++i) {
            double v = sv[i]; int ei = sc[i];
            if (v > b0 || (v == b0 && ei < i0)) { b1 = b0; i1 = i0; b0 = v; i0 = ei; }
            else if (v > b1 || (v == b1 && ei < i1)) { b1 = v; i1 = ei; }
        }
        double ex = exp(b1 - b0);
        ridx[n * 2 + 0] = i0; ridx[n * 2 + 1] = i1;
        rprob[n * 2 + 0] = (float)(1.0 / (1.0 + ex));
        rprob[n * 2 + 1] = (float)(ex / (1.0 + ex));
    }
}

// ---------------------------------------------------------------------------
// Expert: Y = sum_t p_t * A_t X B_t^T via 32x32x16 bf16 MFMA with residual
// splits (X,T,A,B each split h+l; l*l terms dropped) -> fp32-grade accuracy.
// grid = N/4, block 256 (one wave per token). T round-trips through LDS.
// ---------------------------------------------------------------------------
__global__ __launch_bounds__(256)
void expert_mfma(const float* __restrict__ x, const float* __restrict__ Ae,
                 const float* __restrict__ Be, const int* __restrict__ ridx,
                 const float* __restrict__ rprob, const float* __restrict__ scale,
                 const float* __restrict__ bias, float* __restrict__ out)
{
    __shared__ __align__(16) float Ts[4][32 * 36];
    const int tid = threadIdx.x, lane = tid & 63, wv = tid >> 6;
    const int n = blockIdx.x * 4 + wv;
    const int col = lane & 31, hi = lane >> 5;

    // X fragments (B-operand of step1): lane holds X[ks*16+hi*8+j][col]
    const float* xr = x + (size_t)n * KD;
    s16x8 Xh[2], Xl[2];
    #pragma unroll
    for (int ks = 0; ks < 2; ++ks)
        #pragma unroll
        for (int j = 0; j < 8; ++j) {
            int i = ks * 16 + hi * 8 + j;
            float v = xr[i * 32 + col];
            short h = f2bf(v);
            Xh[ks][j] = h;
            Xl[ks][j] = f2bf(v - bf2f(h));
        }

    f32x16 accY;
    #pragma unroll
    for (int r = 0; r < 16; ++r) accY[r] = 0.f;

    #pragma unroll
    for (int t = 0; t < 2; ++t) {
        const int   ei = ridx[(size_t)n * 2 + t];
        const float p  = rprob[(size_t)n * 2 + t];
        const float* ap = Ae + (size_t)ei * 1024;
        const float* bp = Be + (size_t)ei * 1024;
        s16x8 Ah[2], Al[2], Bh[2], Bl[2];
        #pragma unroll
        for (int ks = 0; ks < 2; ++ks) {
            const float* arow = ap + col * 32 + ks * 16 + hi * 8;
            float4 a0 = *(const float4*)arow;
            float4 a1 = *(const float4*)(arow + 4);
            const float av[8] = {a0.x, a0.y, a0.z, a0.w, a1.x, a1.y, a1.z, a1.w};
            const float* brow = bp + col * 32 + ks * 16 + hi * 8;
            float4 b0 = *(const float4*)brow;
            float4 b1 = *(const float4*)(brow + 4);
            const float bw[8] = {b0.x, b0.y, b0.z, b0.w, b1.x, b1.y, b1.z, b1.w};
            #pragma unroll
            for (int j = 0; j < 8; ++j) {
                short h = f2bf(av[j]); Ah[ks][j] = h; Al[ks][j] = f2bf(av[j] - bf2f(h));
                h = f2bf(bw[j]);       Bh[ks][j] = h; Bl[ks][j] = f2bf(bw[j] - bf2f(h));
            }
        }
        // step1: T = A @ X
        f32x16 accT;
        #pragma unroll
        for (int r = 0; r < 16; ++r) accT[r] = 0.f;
        #pragma unroll
        for (int ks = 0; ks < 2; ++ks) {
            accT = __builtin_amdgcn_mfma_f32_32x32x16_bf16(Ah[ks], Xh[ks], accT, 0, 0, 0);
            accT = __builtin_amdgcn_mfma_f32_32x32x16_bf16(Ah[ks], Xl[ks], accT, 0, 0, 0);
            accT = __builtin_amdgcn_mfma_f32_32x32x16_bf16(Al[ks], Xh[ks], accT, 0, 0, 0);
        }
        __syncthreads();  // prev iteration's T reads done before overwrite
        #pragma unroll
        for (int r = 0; r < 16; ++r) {
            const int o = (r & 3) + 8 * (r >> 2) + 4 * hi;  // C row mapping
            Ts[wv][o * 36 + col] = accT[r] * p;             // prob applied in fp32
        }
        __syncthreads();
        // re-read T as A-operand: lane holds T[col][ks*16+hi*8+j]
        s16x8 Th[2], Tl[2];
        #pragma unroll
        for (int ks = 0; ks < 2; ++ks) {
            const float* trow = &Ts[wv][col * 36 + ks * 16 + hi * 8];
            float4 t0 = *(const float4*)trow;
            float4 t1 = *(const float4*)(trow + 4);
            const float tw[8] = {t0.x, t0.y, t0.z, t0.w, t1.x, t1.y, t1.z, t1.w};
            #pragma unroll
            for (int j = 0; j < 8; ++j) {
                short h = f2bf(tw[j]); Th[ks][j] = h; Tl[ks][j] = f2bf(tw[j] - bf2f(h));
            }
        }
        // step2: Y += T @ B^T
        #pragma unroll
        for (int ks = 0; ks < 2; ++ks) {
            accY = __builtin_amdgcn_mfma_f32_32x32x16_bf16(Th[ks], Bh[ks], accY, 0, 0, 0);
            accY = __builtin_amdgcn_mfma_f32_32x32x16_bf16(Tl[ks], Bh[ks], accY, 0, 0, 0);
            accY = __builtin_amdgcn_mfma_f32_32x32x16_bf16(Th[ks], Bl[ks], accY, 0, 0, 0);
        }
    }
    const float scl = scale[0];
    float* orow = out + (size_t)n * KD;
    #pragma unroll
    for (int r = 0; r < 16; ++r) {
        const int o = (r & 3) + 8 * (r >> 2) + 4 * hi;
        orow[o * 32 + col] = accY[r] * scl + bias[o * 32 + col];
    }
}

extern "C" void kernel_launch(void* const* d_in, const int* in_sizes, int n_in,
                              void* d_out, int out_size, void* d_ws, size_t ws_size,
                              hipStream_t stream)
{
    const float* x     = (const float*)d_in[0];
    const float* rw    = (const float*)d_in[1];
    const float* Ae    = (const float*)d_in[2];
    const float* Be    = (const float*)d_in[3];
    const float* scale = (const float*)d_in[4];
    const float* bias  = (const float*)d_in[5];
    float* out = (float*)d_out;

    const int N = in_sizes[0] / KD;   // 16384 tokens

    short* wbf  = (short*)d_ws;                                   // 512 KB
    int*   cand = (int*)((char*)d_ws + (size_t)ED * KD * 2);      // N*8 ints
    int*   ridx = cand + (size_t)N * 8;                           // N*2 ints
    float* rprob = (float*)(ridx + (size_t)N * 2);                // N*2 f32

    wconv_kernel<<<(ED * KD / 4 + 255) / 256, 256, 0, stream>>>(rw, wbf, ED * KD / 4);
    router_mfma<<<N / 32, 256, 0, stream>>>(x, wbf, cand);
    refine8_kernel<<<N, 512, 0, stream>>>(x, rw, cand, ridx, rprob);
    expert_mfma<<<N / 4, 256, 0, stream>>>(x, Ae, Be, ridx, rprob, scale, bias, out);
}

// Round 9
// 237.779 us; speedup vs baseline: 1.6721x; 1.3586x over previous
//
#include <hip/hip_runtime.h>
#include <math.h>

#define KD 1024
#define ED 256

typedef __attribute__((ext_vector_type(8)))  short s16x8;
typedef __attribute__((ext_vector_type(4)))  float f32x4;
typedef __attribute__((ext_vector_type(16))) float f32x16;

__device__ __forceinline__ short f2bf(float f) {
    union { float f; unsigned u; } v; v.f = f;
    unsigned r = v.u + 0x7fffu + ((v.u >> 16) & 1u);
    return (short)(r >> 16);
}
__device__ __forceinline__ float bf2f(short s) {
    union { unsigned u; float f; } v; v.u = ((unsigned)(unsigned short)s) << 16;
    return v.f;
}

// ---------------------------------------------------------------------------
// Convert router_w fp32 -> bf16 once (256K elems).
// ---------------------------------------------------------------------------
__global__ __launch_bounds__(256)
void wconv_kernel(const float* __restrict__ w, short* __restrict__ wb, int n4) {
    int i = blockIdx.x * 256 + threadIdx.x;
    if (i < n4) {
        float4 v = ((const float4*)w)[i];
        short4 o;
        o.x = f2bf(v.x); o.y = f2bf(v.y); o.z = f2bf(v.z); o.w = f2bf(v.w);
        ((short4*)wb)[i] = o;
    }
}

// ---------------------------------------------------------------------------
// Router: 32 tokens x 256 experts per block via 16x16x32 bf16 MFMA.
// (validated in R4 — unchanged)
// ---------------------------------------------------------------------------
__global__ __launch_bounds__(256)
void router_mfma(const float* __restrict__ x, const short* __restrict__ wb,
                 int* __restrict__ cand)
{
    __shared__ __align__(16) char smem[36864];
    char* XsB = smem;            // 32 rows x 128B  (bf16 [tok][k], swizzled)
    char* WsB = smem + 4096;     // 256 rows x 128B (bf16 [e][k],  swizzled)
    float* Ls = (float*)smem;    // 32 x 260 fp32 logits (reuses LDS after K-loop)

    const int tid  = threadIdx.x;
    const int lane = tid & 63;
    const int wv   = tid >> 6;
    const int n0   = blockIdx.x * 32;

    f32x4 acc[2][4];
    #pragma unroll
    for (int i = 0; i < 2; ++i)
        #pragma unroll
        for (int j = 0; j < 4; ++j)
            #pragma unroll
            for (int r = 0; r < 4; ++r) acc[i][j][r] = 0.f;

    const int stok = tid >> 3;        // 0..31 staging row
    const int skq  = (tid & 7) * 8;   // k offset 0..56
    const int xswz = (stok & 7) << 4;

    for (int ch = 0; ch < 16; ++ch) {
        {
            const float* xp = x + (size_t)(n0 + stok) * KD + ch * 64 + skq;
            float4 a = *(const float4*)xp;
            float4 b = *(const float4*)(xp + 4);
            s16x8 pk;
            pk[0] = f2bf(a.x); pk[1] = f2bf(a.y); pk[2] = f2bf(a.z); pk[3] = f2bf(a.w);
            pk[4] = f2bf(b.x); pk[5] = f2bf(b.y); pk[6] = f2bf(b.z); pk[7] = f2bf(b.w);
            *(s16x8*)(XsB + stok * 128 + ((skq * 2) ^ xswz)) = pk;
        }
        #pragma unroll
        for (int p = 0; p < 8; ++p) {
            const int e = p * 32 + stok % 32;
            s16x8 v = *(const s16x8*)(wb + (size_t)e * KD + ch * 64 + skq);
            *(s16x8*)(WsB + e * 128 + ((skq * 2) ^ ((e & 7) << 4))) = v;
        }
        __syncthreads();
        #pragma unroll
        for (int ks = 0; ks < 2; ++ks) {
            const int kbyte = ks * 64 + (lane >> 4) * 16;
            s16x8 af[2];
            #pragma unroll
            for (int fm = 0; fm < 2; ++fm) {
                const int tok = fm * 16 + (lane & 15);
                af[fm] = *(const s16x8*)(XsB + tok * 128 + (kbyte ^ ((tok & 7) << 4)));
            }
            #pragma unroll
            for (int fn = 0; fn < 4; ++fn) {
                const int e = wv * 64 + fn * 16 + (lane & 15);
                s16x8 bf = *(const s16x8*)(WsB + e * 128 + (kbyte ^ ((e & 7) << 4)));
                #pragma unroll
                for (int fm = 0; fm < 2; ++fm)
                    acc[fm][fn] = __builtin_amdgcn_mfma_f32_16x16x32_bf16(
                        af[fm], bf, acc[fm][fn], 0, 0, 0);
            }
        }
        __syncthreads();
    }

    #pragma unroll
    for (int fm = 0; fm < 2; ++fm)
        #pragma unroll
        for (int fn = 0; fn < 4; ++fn)
            #pragma unroll
            for (int r = 0; r < 4; ++r) {
                const int tok = fm * 16 + (lane >> 4) * 4 + r;
                const int e   = wv * 64 + fn * 16 + (lane & 15);
                Ls[tok * 260 + e] = acc[fm][fn][r];
            }
    __syncthreads();

    const int t = tid >> 3;   // token 0..31
    const int s = tid & 7;    // segment
    float vv[8]; int ee[8];
    #pragma unroll
    for (int i = 0; i < 8; ++i) { vv[i] = -INFINITY; ee[i] = 0x7fffffff; }
    for (int q = 0; q < 32; ++q) {
        float tv = Ls[t * 260 + s * 32 + q];
        int   te = s * 32 + q;
        if ((tv > vv[7]) || (tv == vv[7] && te < ee[7])) {
            #pragma unroll
            for (int i = 0; i < 8; ++i) {
                bool g = (tv > vv[i]) || (tv == vv[i] && te < ee[i]);
                float fv = g ? vv[i] : tv; int fe = g ? ee[i] : te;
                vv[i] = g ? tv : vv[i];    ee[i] = g ? te : ee[i];
                tv = fv; te = fe;
            }
        }
    }
    int cnt = 0;
    #pragma unroll
    for (int it = 0; it < 8; ++it) {
        float cv = vv[0]; int ce = ee[0];
        #pragma unroll
        for (int i = 1; i < 8; ++i) {
            bool b = (cnt == i); cv = b ? vv[i] : cv; ce = b ? ee[i] : ce;
        }
        float bv = cv; int be = ce;
        #pragma unroll
        for (int m = 1; m <= 4; m <<= 1) {
            float ov = __shfl_xor(bv, m, 64);
            int   oe = __shfl_xor(be, m, 64);
            bool g = (ov > bv) || (ov == bv && oe < be);
            bv = g ? ov : bv; be = g ? oe : be;
        }
        if ((be >> 5) == s) cnt++;
        if (s == 0) cand[(size_t)(n0 + t) * 8 + it] = be;
    }
}

// ---------------------------------------------------------------------------
// Refine v2: 8 tokens/block, one wave per token. x row in regs, 8 candidate
// fp64 dots fully unrolled (8-way ILP), butterflies, exact top-2 + softmax.
// Same math/ordering as validated refine8. grid = N/8, block 512.
// ---------------------------------------------------------------------------
__global__ __launch_bounds__(512)
void refine8_kernel(const float* __restrict__ x, const float* __restrict__ w,
                    const int* __restrict__ cand, int* __restrict__ ridx,
                    float* __restrict__ rprob)
{
    const int tid  = threadIdx.x;
    const int wv   = tid >> 6;
    const int lane = tid & 63;
    const int n    = blockIdx.x * 8 + wv;

    int ce[8];
    #pragma unroll
    for (int c = 0; c < 8; ++c) ce[c] = cand[(size_t)n * 8 + c];

    const float* xr = x + (size_t)n * KD;
    float xf[16];
    #pragma unroll
    for (int i = 0; i < 16; ++i) xf[i] = xr[lane + i * 64];

    double acc[8];
    #pragma unroll
    for (int c = 0; c < 8; ++c) {
        const float* wr = w + (size_t)ce[c] * KD;
        double a = 0.0;
        #pragma unroll
        for (int i = 0; i < 16; ++i)
            a += (double)xf[i] * (double)wr[lane + i * 64];
        acc[c] = a;
    }
    #pragma unroll
    for (int c = 0; c < 8; ++c) {
        #pragma unroll
        for (int m = 32; m >= 1; m >>= 1) acc[c] += __shfl_xor(acc[c], m, 64);
    }
    if (lane == 0) {
        double b0 = -1e300, b1 = -1e300; int i0 = 0x7fffffff, i1 = 0x7fffffff;
        #pragma unroll
        for (int i = 0; i < 8; ++i) {
            double v = acc[i]; int ei = ce[i];
            if (v > b0 || (v == b0 && ei < i0)) { b1 = b0; i1 = i0; b0 = v; i0 = ei; }
            else if (v > b1 || (v == b1 && ei < i1)) { b1 = v; i1 = ei; }
        }
        double ex = exp(b1 - b0);
        ridx[n * 2 + 0] = i0; ridx[n * 2 + 1] = i1;
        rprob[n * 2 + 0] = (float)(1.0 / (1.0 + ex));
        rprob[n * 2 + 1] = (float)(ex / (1.0 + ex));
    }
}

// ---------------------------------------------------------------------------
// Expert v2: same split-bf16 MFMA math as R4, but x/A/B fragments routed
// through a wave-private LDS buffer filled with coalesced float4 loads
// (stride-36 rows -> conflict-free ds_read_b128: col*9 mod 32 bijective).
// Wave-level lgkmcnt sync instead of block barriers. grid = N/4, block 256.
// ---------------------------------------------------------------------------
__global__ __launch_bounds__(256)
void expert_mfma(const float* __restrict__ x, const float* __restrict__ Ae,
                 const float* __restrict__ Be, const int* __restrict__ ridx,
                 const float* __restrict__ rprob, const float* __restrict__ scale,
                 const float* __restrict__ bias, float* __restrict__ out)
{
    __shared__ __align__(16) float Ts[4][32 * 36];
    __shared__ __align__(16) float Sb[4][32 * 36];
    const int tid = threadIdx.x, lane = tid & 63, wv = tid >> 6;
    const int n = blockIdx.x * 4 + wv;
    const int col = lane & 31, hi = lane >> 5;
    float* sb = Sb[wv];
    float* ts = Ts[wv];

    // ---- stage x (coalesced) and build X fragments: X[i][col] ----
    const float* xr = x + (size_t)n * KD;
    #pragma unroll
    for (int it = 0; it < 4; ++it) {
        const int idx = it * 64 + lane;
        float4 v = *(const float4*)(xr + idx * 4);
        *(float4*)&sb[(idx >> 3) * 36 + (idx & 7) * 4] = v;
    }
    asm volatile("s_waitcnt lgkmcnt(0)" ::: "memory");
    s16x8 Xh[2], Xl[2];
    #pragma unroll
    for (int ks = 0; ks < 2; ++ks)
        #pragma unroll
        for (int j = 0; j < 8; ++j) {
            float v = sb[(ks * 16 + hi * 8 + j) * 36 + col];
            short h = f2bf(v);
            Xh[ks][j] = h;
            Xl[ks][j] = f2bf(v - bf2f(h));
        }

    f32x16 accY;
    #pragma unroll
    for (int r = 0; r < 16; ++r) accY[r] = 0.f;

    #pragma unroll
    for (int t = 0; t < 2; ++t) {
        const int   ei = ridx[(size_t)n * 2 + t];
        const float p  = rprob[(size_t)n * 2 + t];
        const float* ap = Ae + (size_t)ei * 1024;
        const float* bp = Be + (size_t)ei * 1024;

        // ---- stage A (coalesced), read A frags: A[col][ks*16+hi*8+j] ----
        #pragma unroll
        for (int it = 0; it < 4; ++it) {
            const int idx = it * 64 + lane;
            float4 v = *(const float4*)(ap + idx * 4);
            *(float4*)&sb[(idx >> 3) * 36 + (idx & 7) * 4] = v;
        }
        asm volatile("s_waitcnt lgkmcnt(0)" ::: "memory");
        s16x8 Ah[2], Al[2];
        #pragma unroll
        for (int ks = 0; ks < 2; ++ks) {
            float4 a0 = *(const float4*)&sb[col * 36 + ks * 16 + hi * 8];
            float4 a1 = *(const float4*)&sb[col * 36 + ks * 16 + hi * 8 + 4];
            const float av[8] = {a0.x, a0.y, a0.z, a0.w, a1.x, a1.y, a1.z, a1.w};
            #pragma unroll
            for (int j = 0; j < 8; ++j) {
                short h = f2bf(av[j]);
                Ah[ks][j] = h; Al[ks][j] = f2bf(av[j] - bf2f(h));
            }
        }
        // ---- stage B (coalesced), read B frags ----
        #pragma unroll
        for (int it = 0; it < 4; ++it) {
            const int idx = it * 64 + lane;
            float4 v = *(const float4*)(bp + idx * 4);
            *(float4*)&sb[(idx >> 3) * 36 + (idx & 7) * 4] = v;
        }
        asm volatile("s_waitcnt lgkmcnt(0)" ::: "memory");
        s16x8 Bh[2], Bl[2];
        #pragma unroll
        for (int ks = 0; ks < 2; ++ks) {
            float4 b0 = *(const float4*)&sb[col * 36 + ks * 16 + hi * 8];
            float4 b1 = *(const float4*)&sb[col * 36 + ks * 16 + hi * 8 + 4];
            const float bw[8] = {b0.x, b0.y, b0.z, b0.w, b1.x, b1.y, b1.z, b1.w};
            #pragma unroll
            for (int j = 0; j < 8; ++j) {
                short h = f2bf(bw[j]);
                Bh[ks][j] = h; Bl[ks][j] = f2bf(bw[j] - bf2f(h));
            }
        }
        // ---- step1: T = A @ X (split) ----
        f32x16 accT;
        #pragma unroll
        for (int r = 0; r < 16; ++r) accT[r] = 0.f;
        #pragma unroll
        for (int ks = 0; ks < 2; ++ks) {
            accT = __builtin_amdgcn_mfma_f32_32x32x16_bf16(Ah[ks], Xh[ks], accT, 0, 0, 0);
            accT = __builtin_amdgcn_mfma_f32_32x32x16_bf16(Ah[ks], Xl[ks], accT, 0, 0, 0);
            accT = __builtin_amdgcn_mfma_f32_32x32x16_bf16(Al[ks], Xh[ks], accT, 0, 0, 0);
        }
        // ---- T round-trip through wave-private LDS (prob applied fp32) ----
        #pragma unroll
        for (int r = 0; r < 16; ++r) {
            const int o = (r & 3) + 8 * (r >> 2) + 4 * hi;
            ts[o * 36 + col] = accT[r] * p;
        }
        asm volatile("s_waitcnt lgkmcnt(0)" ::: "memory");
        s16x8 Th[2], Tl[2];
        #pragma unroll
        for (int ks = 0; ks < 2; ++ks) {
            float4 t0 = *(const float4*)&ts[col * 36 + ks * 16 + hi * 8];
            float4 t1 = *(const float4*)&ts[col * 36 + ks * 16 + hi * 8 + 4];
            const float tw[8] = {t0.x, t0.y, t0.z, t0.w, t1.x, t1.y, t1.z, t1.w};
            #pragma unroll
            for (int j = 0; j < 8; ++j) {
                short h = f2bf(tw[j]);
                Th[ks][j] = h; Tl[ks][j] = f2bf(tw[j] - bf2f(h));
            }
        }
        // ---- step2: Y += T @ B^T (split) ----
        #pragma unroll
        for (int ks = 0; ks < 2; ++ks) {
            accY = __builtin_amdgcn_mfma_f32_32x32x16_bf16(Th[ks], Bh[ks], accY, 0, 0, 0);
            accY = __builtin_amdgcn_mfma_f32_32x32x16_bf16(Tl[ks], Bh[ks], accY, 0, 0, 0);
            accY = __builtin_amdgcn_mfma_f32_32x32x16_bf16(Th[ks], Bl[ks], accY, 0, 0, 0);
        }
    }
    const float scl = scale[0];
    float* orow = out + (size_t)n * KD;
    #pragma unroll
    for (int r = 0; r < 16; ++r) {
        const int o = (r & 3) + 8 * (r >> 2) + 4 * hi;
        orow[o * 32 + col] = accY[r] * scl + bias[o * 32 + col];
    }
}

extern "C" void kernel_launch(void* const* d_in, const int* in_sizes, int n_in,
                              void* d_out, int out_size, void* d_ws, size_t ws_size,
                              hipStream_t stream)
{
    const float* x     = (const float*)d_in[0];
    const float* rw    = (const float*)d_in[1];
    const float* Ae    = (const float*)d_in[2];
    const float* Be    = (const float*)d_in[3];
    const float* scale = (const float*)d_in[4];
    const float* bias  = (const float*)d_in[5];
    float* out = (float*)d_out;

    const int N = in_sizes[0] / KD;   // 16384 tokens

    short* wbf  = (short*)d_ws;                                   // 512 KB
    int*   cand = (int*)((char*)d_ws + (size_t)ED * KD * 2);      // N*8 ints
    int*   ridx = cand + (size_t)N * 8;                           // N*2 ints
    float* rprob = (float*)(ridx + (size_t)N * 2);                // N*2 f32

    wconv_kernel<<<(ED * KD / 4 + 255) / 256, 256, 0, stream>>>(rw, wbf, ED * KD / 4);
    router_mfma<<<N / 32, 256, 0, stream>>>(x, wbf, cand);
    refine8_kernel<<<N / 8, 512, 0, stream>>>(x, rw, cand, ridx, rprob);
    expert_mfma<<<N / 4, 256, 0, stream>>>(x, Ae, Be, ridx, rprob, scale, bias, out);
}

// Round 10
// 206.557 us; speedup vs baseline: 1.9248x; 1.1512x over previous
//
#include <hip/hip_runtime.h>
#include <math.h>

#define KD 1024
#define ED 256

typedef __attribute__((ext_vector_type(8)))  short s16x8;
typedef __attribute__((ext_vector_type(4)))  float f32x4;
typedef __attribute__((ext_vector_type(16))) float f32x16;

__device__ __forceinline__ short f2bf(float f) {
    union { float f; unsigned u; } v; v.f = f;
    unsigned r = v.u + 0x7fffu + ((v.u >> 16) & 1u);
    return (short)(r >> 16);
}
__device__ __forceinline__ float bf2f(short s) {
    union { unsigned u; float f; } v; v.u = ((unsigned)(unsigned short)s) << 16;
    return v.f;
}

// ---------------------------------------------------------------------------
// Convert router_w fp32 -> bf16 once (256K elems).
// ---------------------------------------------------------------------------
__global__ __launch_bounds__(256)
void wconv_kernel(const float* __restrict__ w, short* __restrict__ wb, int n4) {
    int i = blockIdx.x * 256 + threadIdx.x;
    if (i < n4) {
        float4 v = ((const float4*)w)[i];
        short4 o;
        o.x = f2bf(v.x); o.y = f2bf(v.y); o.z = f2bf(v.z); o.w = f2bf(v.w);
        ((short4*)wb)[i] = o;
    }
}

// ---------------------------------------------------------------------------
// Router v3: 32 tokens x 128 experts (one expert-half) per block.
// grid = (N/32)*2 -> 1024 blocks = 4 blocks/CU (16 waves/CU, 50% occ cap).
// Double-buffered LDS (W 2x16KB + X 2x4KB = 40KB), issue-early prefetch of
// chunk ch+1 before MFMA on ch, ONE barrier per chunk. Each half emits its
// bf16 top-4; union of halves' top-4 contains true top-2 (exact fp64 refine
// downstream unchanged).
// ---------------------------------------------------------------------------
__global__ __launch_bounds__(256)
void router_mfma(const float* __restrict__ x, const short* __restrict__ wb,
                 int* __restrict__ cand)
{
    __shared__ __align__(16) char smem[40960];
    char* Wbase = smem;            // 2 x [128 rows x 128B], swizzled
    char* Xbase = smem + 32768;    // 2 x [32 rows x 128B], swizzled
    float* Ls = (float*)smem;      // 32 x 132 fp32 logits (reused after loop)

    const int tid  = threadIdx.x;
    const int lane = tid & 63;
    const int wv   = tid >> 6;
    const int bid  = blockIdx.x;
    const int n0   = (bid >> 1) * 32;   // token tile
    const int half = bid & 1;           // expert half
    const int e0   = half * 128;

    f32x4 acc[2][2];
    #pragma unroll
    for (int i = 0; i < 2; ++i)
        #pragma unroll
        for (int j = 0; j < 2; ++j)
            #pragma unroll
            for (int r = 0; r < 4; ++r) acc[i][j][r] = 0.f;

    // staging indices
    const int wrow = tid >> 3;          // 0..31 (W row group base, X token)
    const int b16  = (tid & 7) * 16;    // byte-in-chunk for W (16B units)
    const int k8   = (tid & 7) * 8;     // k-offset for X (8 floats)
    const int wswz = (wrow & 7) << 4;   // row&7 swizzle (rows step by 32 == 0 mod 8)

    // ---- prologue: stage chunk 0 into buf 0 ----
    {
        s16x8 wreg[4];
        #pragma unroll
        for (int q = 0; q < 4; ++q)
            wreg[q] = *(const s16x8*)(wb + (size_t)(e0 + wrow + q * 32) * KD + (tid & 7) * 8);
        const float* xp = x + (size_t)(n0 + wrow) * KD + k8;
        float4 xa = *(const float4*)xp;
        float4 xb = *(const float4*)(xp + 4);
        #pragma unroll
        for (int q = 0; q < 4; ++q)
            *(s16x8*)(Wbase + (wrow + q * 32) * 128 + (b16 ^ wswz)) = wreg[q];
        s16x8 pk;
        pk[0]=f2bf(xa.x); pk[1]=f2bf(xa.y); pk[2]=f2bf(xa.z); pk[3]=f2bf(xa.w);
        pk[4]=f2bf(xb.x); pk[5]=f2bf(xb.y); pk[6]=f2bf(xb.z); pk[7]=f2bf(xb.w);
        *(s16x8*)(Xbase + wrow * 128 + ((k8 * 2) ^ wswz)) = pk;
    }
    __syncthreads();

    int cur = 0;
    const int frow = lane & 15;
    const int fswz = (lane & 7) << 4;
    for (int ch = 0; ch < 16; ++ch) {
        char* Wc = Wbase + cur * 16384;
        char* Xc = Xbase + cur * 4096;
        char* Wn = Wbase + (cur ^ 1) * 16384;
        char* Xn = Xbase + (cur ^ 1) * 4096;
        const bool pf = (ch < 15);

        // issue next-chunk global loads early (hide L2 latency under MFMA)
        s16x8 wreg[4];
        float4 xa, xb;
        if (pf) {
            const int ch1 = ch + 1;
            #pragma unroll
            for (int q = 0; q < 4; ++q)
                wreg[q] = *(const s16x8*)(wb + (size_t)(e0 + wrow + q * 32) * KD + ch1 * 64 + (tid & 7) * 8);
            const float* xp = x + (size_t)(n0 + wrow) * KD + ch1 * 64 + k8;
            xa = *(const float4*)xp;
            xb = *(const float4*)(xp + 4);
        }

        // compute on current buffers
        #pragma unroll
        for (int ks = 0; ks < 2; ++ks) {
            const int kb  = ks * 64 + (lane >> 4) * 16;
            const int kbs = kb ^ fswz;
            s16x8 af0 = *(const s16x8*)(Xc + frow * 128 + kbs);
            s16x8 af1 = *(const s16x8*)(Xc + (16 + frow) * 128 + kbs);
            s16x8 bf0 = *(const s16x8*)(Wc + (wv * 32 + frow) * 128 + kbs);
            s16x8 bf1 = *(const s16x8*)(Wc + (wv * 32 + 16 + frow) * 128 + kbs);
            acc[0][0] = __builtin_amdgcn_mfma_f32_16x16x32_bf16(af0, bf0, acc[0][0], 0, 0, 0);
            acc[0][1] = __builtin_amdgcn_mfma_f32_16x16x32_bf16(af0, bf1, acc[0][1], 0, 0, 0);
            acc[1][0] = __builtin_amdgcn_mfma_f32_16x16x32_bf16(af1, bf0, acc[1][0], 0, 0, 0);
            acc[1][1] = __builtin_amdgcn_mfma_f32_16x16x32_bf16(af1, bf1, acc[1][1], 0, 0, 0);
        }

        // write prefetched chunk into next buffers
        if (pf) {
            #pragma unroll
            for (int q = 0; q < 4; ++q)
                *(s16x8*)(Wn + (wrow + q * 32) * 128 + (b16 ^ wswz)) = wreg[q];
            s16x8 pk;
            pk[0]=f2bf(xa.x); pk[1]=f2bf(xa.y); pk[2]=f2bf(xa.z); pk[3]=f2bf(xa.w);
            pk[4]=f2bf(xb.x); pk[5]=f2bf(xb.y); pk[6]=f2bf(xb.z); pk[7]=f2bf(xb.w);
            *(s16x8*)(Xn + wrow * 128 + ((k8 * 2) ^ wswz)) = pk;
        }
        __syncthreads();
        cur ^= 1;
    }

    // ---- dump logits: C layout col=lane&15 (expert), row=(lane>>4)*4+r (token)
    #pragma unroll
    for (int fm = 0; fm < 2; ++fm)
        #pragma unroll
        for (int fn = 0; fn < 2; ++fn)
            #pragma unroll
            for (int r = 0; r < 4; ++r) {
                const int tok = fm * 16 + (lane >> 4) * 4 + r;
                const int e   = wv * 32 + fn * 16 + (lane & 15);
                Ls[tok * 132 + e] = acc[fm][fn][r];
            }
    __syncthreads();

    // ---- per-token top-4 of this half: 8 threads/token, 16 experts each ----
    const int t8 = tid >> 3;   // token 0..31
    const int sg = tid & 7;    // segment
    float vv0=-INFINITY, vv1=-INFINITY, vv2=-INFINITY, vv3=-INFINITY;
    int   ee0=0x7fffffff, ee1=0x7fffffff, ee2=0x7fffffff, ee3=0x7fffffff;
    #pragma unroll
    for (int q = 0; q < 16; ++q) {
        const float tv = Ls[t8 * 132 + sg * 16 + q];
        const int   te = sg * 16 + q;
        if ((tv > vv3) || (tv == vv3 && te < ee3)) {
            const bool g0 = (tv > vv0) || (tv == vv0 && te < ee0);
            const bool g1 = (tv > vv1) || (tv == vv1 && te < ee1);
            const bool g2 = (tv > vv2) || (tv == vv2 && te < ee2);
            if (g0)      { vv3=vv2;ee3=ee2; vv2=vv1;ee2=ee1; vv1=vv0;ee1=ee0; vv0=tv;ee0=te; }
            else if (g1) { vv3=vv2;ee3=ee2; vv2=vv1;ee2=ee1; vv1=tv;ee1=te; }
            else if (g2) { vv3=vv2;ee3=ee2; vv2=tv;ee2=te; }
            else         { vv3=tv;ee3=te; }
        }
    }
    // merge sorted-4 lists across the 8-thread group
    #pragma unroll
    for (int m = 1; m <= 4; m <<= 1) {
        const float u0=__shfl_xor(vv0,m,64), u1=__shfl_xor(vv1,m,64),
                    u2=__shfl_xor(vv2,m,64), u3=__shfl_xor(vv3,m,64);
        const int   f0=__shfl_xor(ee0,m,64), f1=__shfl_xor(ee1,m,64),
                    f2=__shfl_xor(ee2,m,64), f3=__shfl_xor(ee3,m,64);
        float av[4]={vv0,vv1,vv2,vv3}, bv[4]={u0,u1,u2,u3};
        int   ae[4]={ee0,ee1,ee2,ee3}, be[4]={f0,f1,f2,f3};
        float rv[4]; int re[4]; int pa=0, pb=0;
        #pragma unroll
        for (int k2 = 0; k2 < 4; ++k2) {
            const float va=av[pa], vb=bv[pb];
            const int   ia=ae[pa], ib=be[pb];
            const bool ta = (va > vb) || (va == vb && ia < ib);
            rv[k2] = ta ? va : vb; re[k2] = ta ? ia : ib;
            pa += ta ? 1 : 0; pb += ta ? 0 : 1;
        }
        vv0=rv[0];vv1=rv[1];vv2=rv[2];vv3=rv[3];
        ee0=re[0];ee1=re[1];ee2=re[2];ee3=re[3];
    }
    if (sg == 0) {
        int* cp = cand + (size_t)(n0 + t8) * 8 + half * 4;
        cp[0] = e0 + ee0; cp[1] = e0 + ee1; cp[2] = e0 + ee2; cp[3] = e0 + ee3;
    }
}

// ---------------------------------------------------------------------------
// Refine v2: 8 tokens/block, one wave per token. x row in regs, 8 candidate
// fp64 dots fully unrolled (8-way ILP), butterflies, exact top-2 + softmax.
// grid = N/8, block 512.  (validated R9 — unchanged)
// ---------------------------------------------------------------------------
__global__ __launch_bounds__(512)
void refine8_kernel(const float* __restrict__ x, const float* __restrict__ w,
                    const int* __restrict__ cand, int* __restrict__ ridx,
                    float* __restrict__ rprob)
{
    const int tid  = threadIdx.x;
    const int wv   = tid >> 6;
    const int lane = tid & 63;
    const int n    = blockIdx.x * 8 + wv;

    int ce[8];
    #pragma unroll
    for (int c = 0; c < 8; ++c) ce[c] = cand[(size_t)n * 8 + c];

    const float* xr = x + (size_t)n * KD;
    float xf[16];
    #pragma unroll
    for (int i = 0; i < 16; ++i) xf[i] = xr[lane + i * 64];

    double acc[8];
    #pragma unroll
    for (int c = 0; c < 8; ++c) {
        const float* wr = w + (size_t)ce[c] * KD;
        double a = 0.0;
        #pragma unroll
        for (int i = 0; i < 16; ++i)
            a += (double)xf[i] * (double)wr[lane + i * 64];
        acc[c] = a;
    }
    #pragma unroll
    for (int c = 0; c < 8; ++c) {
        #pragma unroll
        for (int m = 32; m >= 1; m >>= 1) acc[c] += __shfl_xor(acc[c], m, 64);
    }
    if (lane == 0) {
        double b0 = -1e300, b1 = -1e300; int i0 = 0x7fffffff, i1 = 0x7fffffff;
        #pragma unroll
        for (int i = 0; i < 8; ++i) {
            double v = acc[i]; int ei = ce[i];
            if (v > b0 || (v == b0 && ei < i0)) { b1 = b0; i1 = i0; b0 = v; i0 = ei; }
            else if (v > b1 || (v == b1 && ei < i1)) { b1 = v; i1 = ei; }
        }
        double ex = exp(b1 - b0);
        ridx[n * 2 + 0] = i0; ridx[n * 2 + 1] = i1;
        rprob[n * 2 + 0] = (float)(1.0 / (1.0 + ex));
        rprob[n * 2 + 1] = (float)(ex / (1.0 + ex));
    }
}

// ---------------------------------------------------------------------------
// Expert v2: split-bf16 MFMA with LDS-staged coalesced gathers.
// grid = N/4, block 256.  (validated R9 — unchanged)
// ---------------------------------------------------------------------------
__global__ __launch_bounds__(256)
void expert_mfma(const float* __restrict__ x, const float* __restrict__ Ae,
                 const float* __restrict__ Be, const int* __restrict__ ridx,
                 const float* __restrict__ rprob, const float* __restrict__ scale,
                 const float* __restrict__ bias, float* __restrict__ out)
{
    __shared__ __align__(16) float Ts[4][32 * 36];
    __shared__ __align__(16) float Sb[4][32 * 36];
    const int tid = threadIdx.x, lane = tid & 63, wv = tid >> 6;
    const int n = blockIdx.x * 4 + wv;
    const int col = lane & 31, hi = lane >> 5;
    float* sb = Sb[wv];
    float* ts = Ts[wv];

    const float* xr = x + (size_t)n * KD;
    #pragma unroll
    for (int it = 0; it < 4; ++it) {
        const int idx = it * 64 + lane;
        float4 v = *(const float4*)(xr + idx * 4);
        *(float4*)&sb[(idx >> 3) * 36 + (idx & 7) * 4] = v;
    }
    asm volatile("s_waitcnt lgkmcnt(0)" ::: "memory");
    s16x8 Xh[2], Xl[2];
    #pragma unroll
    for (int ks = 0; ks < 2; ++ks)
        #pragma unroll
        for (int j = 0; j < 8; ++j) {
            float v = sb[(ks * 16 + hi * 8 + j) * 36 + col];
            short h = f2bf(v);
            Xh[ks][j] = h;
            Xl[ks][j] = f2bf(v - bf2f(h));
        }

    f32x16 accY;
    #pragma unroll
    for (int r = 0; r < 16; ++r) accY[r] = 0.f;

    #pragma unroll
    for (int t = 0; t < 2; ++t) {
        const int   ei = ridx[(size_t)n * 2 + t];
        const float p  = rprob[(size_t)n * 2 + t];
        const float* ap = Ae + (size_t)ei * 1024;
        const float* bp = Be + (size_t)ei * 1024;

        #pragma unroll
        for (int it = 0; it < 4; ++it) {
            const int idx = it * 64 + lane;
            float4 v = *(const float4*)(ap + idx * 4);
            *(float4*)&sb[(idx >> 3) * 36 + (idx & 7) * 4] = v;
        }
        asm volatile("s_waitcnt lgkmcnt(0)" ::: "memory");
        s16x8 Ah[2], Al[2];
        #pragma unroll
        for (int ks = 0; ks < 2; ++ks) {
            float4 a0 = *(const float4*)&sb[col * 36 + ks * 16 + hi * 8];
            float4 a1 = *(const float4*)&sb[col * 36 + ks * 16 + hi * 8 + 4];
            const float av[8] = {a0.x, a0.y, a0.z, a0.w, a1.x, a1.y, a1.z, a1.w};
            #pragma unroll
            for (int j = 0; j < 8; ++j) {
                short h = f2bf(av[j]);
                Ah[ks][j] = h; Al[ks][j] = f2bf(av[j] - bf2f(h));
            }
        }
        #pragma unroll
        for (int it = 0; it < 4; ++it) {
            const int idx = it * 64 + lane;
            float4 v = *(const float4*)(bp + idx * 4);
            *(float4*)&sb[(idx >> 3) * 36 + (idx & 7) * 4] = v;
        }
        asm volatile("s_waitcnt lgkmcnt(0)" ::: "memory");
        s16x8 Bh[2], Bl[2];
        #pragma unroll
        for (int ks = 0; ks < 2; ++ks) {
            float4 b0 = *(const float4*)&sb[col * 36 + ks * 16 + hi * 8];
            float4 b1 = *(const float4*)&sb[col * 36 + ks * 16 + hi * 8 + 4];
            const float bw[8] = {b0.x, b0.y, b0.z, b0.w, b1.x, b1.y, b1.z, b1.w};
            #pragma unroll
            for (int j = 0; j < 8; ++j) {
                short h = f2bf(bw[j]);
                Bh[ks][j] = h; Bl[ks][j] = f2bf(bw[j] - bf2f(h));
            }
        }
        f32x16 accT;
        #pragma unroll
        for (int r = 0; r < 16; ++r) accT[r] = 0.f;
        #pragma unroll
        for (int ks = 0; ks < 2; ++ks) {
            accT = __builtin_amdgcn_mfma_f32_32x32x16_bf16(Ah[ks], Xh[ks], accT, 0, 0, 0);
            accT = __builtin_amdgcn_mfma_f32_32x32x16_bf16(Ah[ks], Xl[ks], accT, 0, 0, 0);
            accT = __builtin_amdgcn_mfma_f32_32x32x16_bf16(Al[ks], Xh[ks], accT, 0, 0, 0);
        }
        #pragma unroll
        for (int r = 0; r < 16; ++r) {
            const int o = (r & 3) + 8 * (r >> 2) + 4 * hi;
            ts[o * 36 + col] = accT[r] * p;
        }
        asm volatile("s_waitcnt lgkmcnt(0)" ::: "memory");
        s16x8 Th[2], Tl[2];
        #pragma unroll
        for (int ks = 0; ks < 2; ++ks) {
            float4 t0 = *(const float4*)&ts[col * 36 + ks * 16 + hi * 8];
            float4 t1 = *(const float4*)&ts[col * 36 + ks * 16 + hi * 8 + 4];
            const float tw[8] = {t0.x, t0.y, t0.z, t0.w, t1.x, t1.y, t1.z, t1.w};
            #pragma unroll
            for (int j = 0; j < 8; ++j) {
                short h = f2bf(tw[j]);
                Th[ks][j] = h; Tl[ks][j] = f2bf(tw[j] - bf2f(h));
            }
        }
        #pragma unroll
        for (int ks = 0; ks < 2; ++ks) {
            accY = __builtin_amdgcn_mfma_f32_32x32x16_bf16(Th[ks], Bh[ks], accY, 0, 0, 0);
            accY = __builtin_amdgcn_mfma_f32_32x32x16_bf16(Tl[ks], Bh[ks], accY, 0, 0, 0);
            accY = __builtin_amdgcn_mfma_f32_32x32x16_bf16(Th[ks], Bl[ks], accY, 0, 0, 0);
        }
    }
    const float scl = scale[0];
    float* orow = out + (size_t)n * KD;
    #pragma unroll
    for (int r = 0; r < 16; ++r) {
        const int o = (r & 3) + 8 * (r >> 2) + 4 * hi;
        orow[o * 32 + col] = accY[r] * scl + bias[o * 32 + col];
    }
}

extern "C" void kernel_launch(void* const* d_in, const int* in_sizes, int n_in,
                              void* d_out, int out_size, void* d_ws, size_t ws_size,
                              hipStream_t stream)
{
    const float* x     = (const float*)d_in[0];
    const float* rw    = (const float*)d_in[1];
    const float* Ae    = (const float*)d_in[2];
    const float* Be    = (const float*)d_in[3];
    const float* scale = (const float*)d_in[4];
    const float* bias  = (const float*)d_in[5];
    float* out = (float*)d_out;

    const int N = in_sizes[0] / KD;   // 16384 tokens

    short* wbf  = (short*)d_ws;                                   // 512 KB
    int*   cand = (int*)((char*)d_ws + (size_t)ED * KD * 2);      // N*8 ints
    int*   ridx = cand + (size_t)N * 8;                           // N*2 ints
    float* rprob = (float*)(ridx + (size_t)N * 2);                // N*2 f32

    wconv_kernel<<<(ED * KD / 4 + 255) / 256, 256, 0, stream>>>(rw, wbf, ED * KD / 4);
    router_mfma<<<(N / 32) * 2, 256, 0, stream>>>(x, wbf, cand);
    refine8_kernel<<<N / 8, 512, 0, stream>>>(x, rw, cand, ridx, rprob);
    expert_mfma<<<N / 4, 256, 0, stream>>>(x, Ae, Be, ridx, rprob, scale, bias, out);
}